// Round 4
// baseline (143.647 us; speedup 1.0000x reference)
//
#include <hip/hip_runtime.h>

// YOLO layer: input [B, A*(5+C), H, W] fp32 -> (boxes [B,N,1,4], confs [B,N,C]) fp32
// B=64, A=3, C=80, H=W=76, N=A*H*W=17328
// d_out = boxes flat (B*N*4) then confs flat (B*N*C)
//
// R3->R4: process 2 y-rows per block (608B contiguous read bursts instead of
// 304B), 512 threads, LDS 52.6KB -> 3 blocks/CU = 24 waves/CU (unchanged).

#define Bn 64
#define An 3
#define Cn 80
#define Hn 76
#define Wn 76
#define HW (Hn * Wn)            // 5776
#define Nn (An * HW)            // 17328
#define CHn (5 + Cn)            // 85
#define Rr 2                    // y-rows per block
#define ROWLEN (Rr * Wn)        // 152 floats staged per channel
#define PITCH 153               // LDS pitch: 153 % 32 = 25, gcd(25,32)=1 -> conflict-free
#define BOX_TOTAL (Bn * Nn * 4) // 4435968 floats
#define NWG (Bn * An * (Hn / Rr)) // 7296 = 8 * 912
#define CPX (NWG / 8)           // 912 blocks per XCD chunk
#define NT4 (CHn * (ROWLEN / 4))  // 3230 float4 staging loads per block
#define NCONF (ROWLEN * Cn)     // 12160 conf elements per block

typedef float floatx4 __attribute__((ext_vector_type(4)));  // nontemporal-store compatible

__device__ __forceinline__ float sigmoidf_(float x) {
    return 1.0f / (1.0f + __expf(-x));
}

__launch_bounds__(512)
__global__ void yolo_kernel(const float* __restrict__ in, float* __restrict__ out) {
    __shared__ float s_in[CHn * PITCH];   // 52,020 B
    __shared__ float s_det[ROWLEN];

    // XCD-aware bijective swizzle: each XCD owns a contiguous (b,a,y) chunk
    const int raw = blockIdx.x;
    const int bid = (raw & 7) * CPX + (raw >> 3);

    const int yb = bid % (Hn / Rr);      // row-pair index
    const int t  = bid / (Hn / Rr);
    const int a  = t % An;
    const int b  = t / An;
    const int y0 = yb * Rr;

    const float aw = (a == 0) ? 1.5f : ((a == 1) ? 2.375f : 5.0f);
    const float ah = (a == 0) ? 2.0f : ((a == 1) ? 4.5f   : 3.5f);

    const int tid = threadIdx.x;
    const float* __restrict__ src =
        in + ((size_t)(b * (An * CHn) + a * CHn)) * HW + (size_t)y0 * Wn;

    // ---- phase 1: stage 85 channels x 152 floats (rows y0,y0+1 contiguous) ----
    for (int i = tid; i < NT4; i += 512) {
        const int ch = i / (ROWLEN / 4);       // /38
        const int q  = i % (ROWLEN / 4);
        const float4 v = *(const float4*)(src + (size_t)ch * HW + q * 4);
        float* d = &s_in[ch * PITCH + q * 4];
        d[0] = v.x; d[1] = v.y; d[2] = v.z; d[3] = v.w;
    }
    __syncthreads();

    const int n_base = a * HW + y0 * Wn;       // 152 consecutive n per block

    // ---- phase 2: boxes + det (152 lanes) ----
    if (tid < ROWLEN) {
        const int x  = (tid < Wn) ? tid : tid - Wn;
        const int yy = y0 + ((tid < Wn) ? 0 : 1);
        const float sx  = sigmoidf_(s_in[0 * PITCH + tid]);
        const float sy  = sigmoidf_(s_in[1 * PITCH + tid]);
        const float ew  = __expf(s_in[2 * PITCH + tid]);
        const float eh  = __expf(s_in[3 * PITCH + tid]);
        const float det = sigmoidf_(s_in[4 * PITCH + tid]);
        s_det[tid] = det;

        const float bx = (sx + (float)x) * (1.0f / Wn);
        const float by = (sy + (float)yy) * (1.0f / Hn);
        const float bw = ew * aw * (1.0f / Wn);
        const float bh = eh * ah * (1.0f / Hn);
        const float bx1 = bx - 0.5f * bw;
        const float by1 = by - 0.5f * bh;

        const size_t n = (size_t)b * Nn + n_base + tid;
        floatx4 box;
        box.x = bx1; box.y = by1; box.z = bx1 + bw; box.w = by1 + bh;
        __builtin_nontemporal_store(box, (floatx4*)(out + n * 4));
    }
    __syncthreads();

    // ---- phase 3: confs, c-fastest -> coalesced nontemporal stores ----
    float* __restrict__ confs = out + BOX_TOTAL + ((size_t)b * Nn + n_base) * Cn;
    for (int i = tid; i < NCONF; i += 512) {
        const int s = i / Cn;
        const int c = i % Cn;
        const float v = sigmoidf_(s_in[(5 + c) * PITCH + s]) * s_det[s];
        __builtin_nontemporal_store(v, confs + i);
    }
}

extern "C" void kernel_launch(void* const* d_in, const int* in_sizes, int n_in,
                              void* d_out, int out_size, void* d_ws, size_t ws_size,
                              hipStream_t stream) {
    (void)in_sizes; (void)n_in; (void)d_ws; (void)ws_size; (void)out_size;
    const float* in = (const float*)d_in[0];
    float* out = (float*)d_out;
    yolo_kernel<<<NWG, 512, 0, stream>>>(in, out);
}

// Round 5
// 143.520 us; speedup vs baseline: 1.0009x; 1.0009x over previous
//
#include <hip/hip_runtime.h>

// YOLO layer: input [B, A*(5+C), H, W] fp32 -> (boxes [B,N,1,4], confs [B,N,C]) fp32
// B=64, A=3, C=80, H=W=76, N=A*H*W=17328
// d_out = boxes flat (B*N*4) then confs flat (B*N*C)
//
// R4->R5: stage cls logits as bf16 in LDS (transpose buffer only) ->
// LDS 26.2KB -> 14.0KB -> 8 blocks/CU (32 waves, was 24). Tests the
// latency/occupancy theory for the 17% gap to copy-ceiling.

#define Bn 64
#define An 3
#define Cn 80
#define Hn 76
#define Wn 76
#define HW (Hn * Wn)            // 5776
#define Nn (An * HW)            // 17328
#define CHn (5 + Cn)            // 85
#define PITCHF 77               // f32 pitch for box channels (conflict-free)
#define PITCHB 76               // bf16 pitch for cls: rows 152B (8B-aligned), 4-way read conflict (cheap)
#define BOX_TOTAL (Bn * Nn * 4) // 4435968 floats
#define NWG (Bn * An * Hn)      // 14592 = 8 * 1824
#define CPX (NWG / 8)           // 1824 blocks per XCD chunk
#define NT4 (CHn * (Wn / 4))    // 1615 float4 staging loads per block
#define NCONF (Wn * Cn)         // 6080 conf elements per block

typedef float floatx4 __attribute__((ext_vector_type(4)));

__device__ __forceinline__ float sigmoidf_(float x) {
    return 1.0f / (1.0f + __expf(-x));
}

__device__ __forceinline__ unsigned short f2bf(float f) {   // RNE f32->bf16
    unsigned u = __float_as_uint(f);
    return (unsigned short)((u + 0x7FFFu + ((u >> 16) & 1u)) >> 16);
}
__device__ __forceinline__ float bf2f(unsigned short h) {
    return __uint_as_float(((unsigned)h) << 16);
}

__launch_bounds__(256)
__global__ void yolo_kernel(const float* __restrict__ in, float* __restrict__ out) {
    __shared__ unsigned short s_cls[Cn * PITCHB];  // 12160 B
    __shared__ float s_box[5 * PITCHF];            // 1540 B
    __shared__ float s_det[Wn];                    // 304 B

    // XCD-aware bijective swizzle: each XCD owns a contiguous (b,a,y) chunk
    const int raw = blockIdx.x;
    const int bid = (raw & 7) * CPX + (raw >> 3);

    const int y = bid % Hn;
    const int t = bid / Hn;
    const int a = t % An;
    const int b = t / An;

    const float aw = (a == 0) ? 1.5f : ((a == 1) ? 2.375f : 5.0f);
    const float ah = (a == 0) ? 2.0f : ((a == 1) ? 4.5f   : 3.5f);

    const int tid = threadIdx.x;
    const float* __restrict__ src =
        in + ((size_t)(b * (An * CHn) + a * CHn)) * HW + (size_t)y * Wn;

    // ---- phase 1: stage 85 channels x 76 floats; cls channels -> bf16 ----
    for (int i = tid; i < NT4; i += 256) {
        const int ch = i / 19;
        const int q  = i % 19;
        const float4 v = *(const float4*)(src + (size_t)ch * HW + q * 4);
        if (ch < 5) {
            float* d = &s_box[ch * PITCHF + q * 4];
            d[0] = v.x; d[1] = v.y; d[2] = v.z; d[3] = v.w;
        } else {
            ushort4 h;
            h.x = f2bf(v.x); h.y = f2bf(v.y); h.z = f2bf(v.z); h.w = f2bf(v.w);
            *(ushort4*)&s_cls[(ch - 5) * PITCHB + q * 4] = h;   // 8B-aligned b64 write
        }
    }
    __syncthreads();

    const int n_base = a * HW + y * Wn;

    // ---- phase 2: boxes + det (76 lanes) ----
    if (tid < Wn) {
        const int x = tid;
        const float sx  = sigmoidf_(s_box[0 * PITCHF + x]);
        const float sy  = sigmoidf_(s_box[1 * PITCHF + x]);
        const float ew  = __expf(s_box[2 * PITCHF + x]);
        const float eh  = __expf(s_box[3 * PITCHF + x]);
        const float det = sigmoidf_(s_box[4 * PITCHF + x]);
        s_det[x] = det;

        const float bx = (sx + (float)x) * (1.0f / Wn);
        const float by = (sy + (float)y) * (1.0f / Hn);
        const float bw = ew * aw * (1.0f / Wn);
        const float bh = eh * ah * (1.0f / Hn);
        const float bx1 = bx - 0.5f * bw;
        const float by1 = by - 0.5f * bh;

        const size_t n = (size_t)b * Nn + n_base + x;
        floatx4 box;
        box.x = bx1; box.y = by1; box.z = bx1 + bw; box.w = by1 + bh;
        __builtin_nontemporal_store(box, (floatx4*)(out + n * 4));
    }
    __syncthreads();

    // ---- phase 3: confs, c-fastest -> coalesced nontemporal stores ----
    float* __restrict__ confs = out + BOX_TOTAL + ((size_t)b * Nn + n_base) * Cn;
    for (int i = tid; i < NCONF; i += 256) {
        const int s = i / Cn;
        const int c = i % Cn;
        const float v = sigmoidf_(bf2f(s_cls[c * PITCHB + s])) * s_det[s];
        __builtin_nontemporal_store(v, confs + i);
    }
}

extern "C" void kernel_launch(void* const* d_in, const int* in_sizes, int n_in,
                              void* d_out, int out_size, void* d_ws, size_t ws_size,
                              hipStream_t stream) {
    (void)in_sizes; (void)n_in; (void)d_ws; (void)ws_size; (void)out_size;
    const float* in = (const float*)d_in[0];
    float* out = (float*)d_out;
    yolo_kernel<<<NWG, 256, 0, stream>>>(in, out);
}